// Round 4
// baseline (159.750 us; speedup 1.0000x reference)
//
#include <hip/hip_runtime.h>
#include <math.h>

#define LOG2PI_F   1.8378770664093453f
#define LOGPI_F    1.1447298858494002f
#define LOG2_F     0.6931471805599453f
#define L2E_F      1.4426950408889634f
#define ERF3OS2    0.9973002039367398f   // erf(3/sqrt(2)), wf = 3.0 (compile-time)
#define WF         3.0f
#define NMC        1024
#define LOGN_F     6.9314718055994531f   // log(1024)
#define LOGGAMMA15 (-0.12078223763524522f) // log(Gamma(1.5))
#define YMIN_F     0.01f                 // global lower bound on y (y = 0.01 + U(0,1))
#define QSKIP_F    13.0f                 // drop 2^bm when 2*y*gc >= 13  (rel err < 2^-13)

#if defined(__has_builtin)
#if __has_builtin(__builtin_amdgcn_exp2f)
#define EXP2(v) __builtin_amdgcn_exp2f(v)
#else
#define EXP2(v) __expf((v) * LOG2_F)
#endif
#else
#define EXP2(v) __expf((v) * LOG2_F)
#endif

// ---------------- Kernel A: per-n tables (partitioned) + header ----------------
// tab[c][idx] = float4 {txc, gc, zc, 0}:
//   txc = inv_sn2 * tx * L2E ; gc = 2*inv_sn2*G*L2E ; zc = (B - 0.5*inv_sn2*tx^2 - inv_sn2*G^2)*L2E
//   B = -log G + lptx + log(I_diff) - log N + lw[3+c]       (validated rounds 1-3)
// s1*log2e = Cm + x*txc + zc + y*gc = bp ; s2*log2e = bp - 2*y*gc = bm ; term = 2^bp - 2^bm.
// Entries with 2*YMIN*gc < QSKIP ("bm matters for some y") are placed at idx < kc;
// the rest (bm provably negligible for ALL y) at idx >= kc. kc -> hdr[9+c].
__global__ void precompute_kernel(const float* __restrict__ ku12,
                                  const float* __restrict__ ku23,
                                  const float* __restrict__ ku13,
                                  const float* __restrict__ sbp,
                                  const float* __restrict__ snp,
                                  const float* __restrict__ I1p,
                                  const float* __restrict__ I2p,
                                  const float* __restrict__ I3p,
                                  const float* __restrict__ w,
                                  float4* __restrict__ tab,
                                  float* __restrict__ hdr,
                                  float* __restrict__ out) {
    __shared__ int cFront[3], cBack[3];
    const int n = threadIdx.x;           // 1024 threads, 1 block
    if (n < 3) { cFront[n] = 0; cBack[n] = 0; }
    __syncthreads();

    const float sigma_b = sbp[0], sigma_n = snp[0];
    const float I1 = I1p[0], I2 = I2p[0], I3 = I3p[0];
    const float inv_sn2 = 1.0f / (sigma_n * sigma_n);

    float wv[6];
    #pragma unroll
    for (int i = 0; i < 6; ++i) wv[i] = w[i];
    float wm = wv[0];
    #pragma unroll
    for (int i = 1; i < 6; ++i) wm = fmaxf(wm, wv[i]);
    float wsum = 0.f;
    #pragma unroll
    for (int i = 0; i < 6; ++i) wsum += __expf(wv[i] - wm);
    const float lsew = wm + __logf(wsum);

    const float* kus[3] = {ku12, ku23, ku13};
    const float Ias[3] = {I1, I2, I1};
    const float Ibs[3] = {I2, I3, I3};
    const float gb = rsqrtf(2.0f * (float)M_PI * sigma_b * sigma_b);

    #pragma unroll
    for (int c = 0; c < 3; ++c) {
        const float Ia = Ias[c], Ib = Ibs[c];
        const float gap = Ib - Ia;
        const float I_min  = Ia + 0.5f * gap * (1.0f - ERF3OS2);
        const float I_diff = gap * ERF3OS2;
        const float add_c  = __logf(I_diff) - LOGN_F + (wv[3 + c] - lsew);
        const float ku = kus[c][n];
        const float tx = ku * I_diff + I_min;
        const float v  = 2.0f * (tx - Ia) / gap - 1.0f;
        const float ei = erfinvf(v);
        const float ei2 = ei * ei;
        const float G   = gap * gb * __expf(-ei2);
        const float lptx = -__logf(2.0f * WF * gap) + 0.5f * LOG2PI_F + ei2;
        const float B = -__logf(G) + lptx + add_c;

        const float txc = inv_sn2 * tx * L2E_F;
        const float gc  = 2.0f * inv_sn2 * G * L2E_F;
        const float zc  = (B - 0.5f * inv_sn2 * tx * tx - inv_sn2 * G * G) * L2E_F;

        const bool needs_bm = (2.0f * YMIN_F * gc < QSKIP_F);
        int idx;
        if (needs_bm) idx = atomicAdd(&cFront[c], 1);
        else          idx = (NMC - 1) - atomicAdd(&cBack[c], 1);
        tab[c * NMC + idx] = make_float4(txc, gc, zc, 0.f);
    }
    __syncthreads();

    if (n == 0) {
        const float lsn = __logf(sigma_n);
        hdr[0] = inv_sn2;
        hdr[1] = -2.f * lsn - 0.5f * LOG2PI_F - 0.5f * LOGPI_F;        // C_A (A_m = C_A + log y)
        hdr[2] = LOG2_F - LOGGAMMA15 - 4.f * lsn - 0.5f * LOG2PI_F;    // K_int
        hdr[3] = I1; hdr[4] = I2; hdr[5] = I3;
        hdr[6] = wv[0] - lsew; hdr[7] = wv[1] - lsew; hdr[8] = wv[2] - lsew;
        hdr[9]  = (float)cFront[0];
        hdr[10] = (float)cFront[1];
        hdr[11] = (float)cFront[2];
        out[0] = 0.f;
    }
}

// ---------------- Kernel B: main loop ----------------
// Block = 512 threads = 8 waves. Lane -> data point m; wave w handles n = w + 8*j.
#define WAVES 8
#define PCH   128   // iterations per wave = NMC / WAVES

__global__ __launch_bounds__(512) void
main_kernel(const float* __restrict__ xg, const float* __restrict__ yg,
            const float4* __restrict__ tab, const float* __restrict__ hdr,
            float* __restrict__ out, int M) {
    const int lane = threadIdx.x & 63;
    const int wave = threadIdx.x >> 6;
    const int m = blockIdx.x * 64 + lane;
    const bool valid = (m < M);
    const float x = valid ? xg[m] : 0.5f;
    const float y = valid ? yg[m] : 0.5f;

    const float inv_sn2 = hdr[0];
    const float Cm = -(fmaf(0.5f * x, x, y * y)) * inv_sn2 * L2E_F;
    const float yn = -y;

    __shared__ float pac[WAVES][3][64];

    #pragma unroll
    for (int c = 0; c < 3; ++c) {
        const float4* tc = tab + c * NMC + wave;
        const int kc = (int)hdr[9 + c];
        int kB = (kc - wave + 7) >> 3;
        kB = (kB < 0) ? 0 : (kB > PCH ? PCH : kB);

        float accA = 0.f, accB = 0.f;
        int j = 0;
        #pragma unroll 2
        for (; j < kB; ++j) {            // entries needing the Bessel-correction exp
            const float4 t = tc[j * 8];
            const float t1 = fmaf(x, t.x, Cm);   // 1 sgpr (t.x)
            const float t2 = t1 + t.z;           // 1 sgpr (t.z)
            const float bp = fmaf(y,  t.y, t2);  // 1 sgpr (t.y)
            const float bm = fmaf(yn, t.y, t2);
            accA += EXP2(bp);
            accB += EXP2(bm);
        }
        #pragma unroll 4
        for (; j < PCH; ++j) {           // bm provably negligible: single exp
            const float4 t = tc[j * 8];
            const float t1 = fmaf(x, t.x, Cm);
            const float t2 = fmaf(y, t.y, t1);
            const float bp = t2 + t.z;
            accA += EXP2(bp);
        }
        pac[wave][c][lane] = accA - accB;
    }
    __syncthreads();

    if (wave == 0) {
        const float ly = __logf(y);
        const float A_m = hdr[1] + ly;
        const float base_int = hdr[2] + 2.f * ly - y * y * inv_sn2;
        float vals[6];
        #pragma unroll
        for (int c = 0; c < 3; ++c) {
            const float dxi = x - hdr[3 + c];
            vals[c] = hdr[6 + c] + base_int - 0.5f * dxi * dxi * inv_sn2;
        }
        #pragma unroll
        for (int c = 0; c < 3; ++c) {
            float s = 0.f;
            #pragma unroll
            for (int wv2 = 0; wv2 < WAVES; ++wv2) s += pac[wv2][c][lane];
            vals[3 + c] = A_m + __logf(fmaxf(s, 1e-38f));
        }
        float mm = vals[0];
        #pragma unroll
        for (int i = 1; i < 6; ++i) mm = fmaxf(mm, vals[i]);
        float se = 0.f;
        #pragma unroll
        for (int i = 0; i < 6; ++i) se += __expf(vals[i] - mm);
        const float log_mix = mm + __logf(se);
        float contrib = valid ? -log_mix : 0.f;
        #pragma unroll
        for (int off = 32; off > 0; off >>= 1) contrib += __shfl_down(contrib, off);
        if (lane == 0) atomicAdd(out, contrib);
    }
}

extern "C" void kernel_launch(void* const* d_in, const int* in_sizes, int n_in,
                              void* d_out, int out_size, void* d_ws, size_t ws_size,
                              hipStream_t stream) {
    const float* x    = (const float*)d_in[0];
    const float* y    = (const float*)d_in[1];
    const float* ku12 = (const float*)d_in[2];
    const float* ku23 = (const float*)d_in[3];
    const float* ku13 = (const float*)d_in[4];
    const float* sb   = (const float*)d_in[5];
    const float* sn   = (const float*)d_in[6];
    const float* I1   = (const float*)d_in[7];
    const float* I2   = (const float*)d_in[8];
    const float* I3   = (const float*)d_in[9];
    const float* w    = (const float*)d_in[10];
    const int M = in_sizes[0];

    float4* tab = (float4*)d_ws;                                   // 3*1024*16B = 48 KB
    float*  hdr = (float*)((char*)d_ws + 3 * NMC * sizeof(float4));
    float*  out = (float*)d_out;

    precompute_kernel<<<1, NMC, 0, stream>>>(ku12, ku23, ku13, sb, sn, I1, I2, I3, w,
                                             tab, hdr, out);
    const int blocks = (M + 63) / 64;
    main_kernel<<<blocks, 512, 0, stream>>>(x, y, tab, hdr, out, M);
}